// Round 5
// baseline (48.100 us; speedup 1.0000x reference)
//
#include <hip/hip_runtime.h>
#include <math.h>

#define LAMBDA_DECAY 0.01f
#define ALPHA 0.95f
#define LN_EPS 1e-5f

// Geometry (reference: M=8192, D=4096).
#define WPB 4        // waves per block in K1
#define RPW 4        // rows per wave in K1
#define NPART 512    // K1 blocks = M/(WPB*RPW)
#define G2 64        // partials per K2 block
#define NP2 8        // NPART/G2

typedef float v4f __attribute__((ext_vector_type(4)));

static __device__ __forceinline__ float wave_sum_all(float v) {
#pragma unroll
    for (int o = 32; o > 0; o >>= 1) v += __shfl_xor(v, o);
    return v;
}

static __device__ float block_sum(float v, float* sh, int nwaves) {
    int lane = threadIdx.x & 63;
    int w = threadIdx.x >> 6;
    v = wave_sum_all(v);
    if (lane == 0) sh[w] = v;
    __syncthreads();
    float r = 0.0f;
    for (int i = 0; i < nwaves; ++i) r += sh[i];
    __syncthreads();
    return r;
}

// K1: single pass over states, software-pipelined.
//  - cur staged in LDS (frees 64 VGPRs for a second row buffer)
//  - row rr+1's 16 float4 loads issued BEFORE row rr's dot/exp/acc compute,
//    so HBM loads stay in flight under compute (latency hiding)
//  - dot uses 4 independent accumulators (chain 256cy -> ~70cy)
//  - states read nontemporal (streamed once; don't thrash L2)
__global__ __launch_bounds__(256, 2) void fused_kernel(
    const float* __restrict__ states, const float* __restrict__ cur,
    const float* __restrict__ weights, const float* __restrict__ ts,
    const float* __restrict__ t_new,
    float* __restrict__ partial, float* __restrict__ partE, float* __restrict__ partS,
    int M, int D, float scale)
{
    __shared__ v4f shbuf[1024];     // 16 KB: cur during main loop; acc combine in epilogue
    __shared__ float shE[WPB], shS[WPB];

    const int wid = threadIdx.x >> 6;
    const int lane = threadIdx.x & 63;
    const int r0 = (blockIdx.x * WPB + wid) * RPW;

    // Stage cur into LDS (block-cooperative).
    const v4f* c4 = (const v4f*)cur;
#pragma unroll
    for (int j = 0; j < 4; ++j)
        shbuf[j * 256 + threadIdx.x] = c4[j * 256 + threadIdx.x];
    __syncthreads();

    v4f acc[16];
#pragma unroll
    for (int j = 0; j < 16; ++j) acc[j] = (v4f)(0.0f);

    float E = 0.0f, S = 0.0f;
    const float tn = t_new[0];

    v4f rv[2][16];
    {
        const v4f* rp = (const v4f*)(states + (size_t)r0 * D);
#pragma unroll
        for (int j = 0; j < 16; ++j)
            rv[0][j] = __builtin_nontemporal_load(&rp[j * 64 + lane]);
    }

#pragma unroll
    for (int rr = 0; rr < RPW; ++rr) {
        const int row = r0 + rr;
        const int cb = rr & 1;       // current buffer (compile-time after unroll)
        const int nb = cb ^ 1;

        // Prefetch next row first: loads in flight during this row's compute.
        if (rr + 1 < RPW) {
            const v4f* rp = (const v4f*)(states + (size_t)(row + 1) * D);
#pragma unroll
            for (int j = 0; j < 16; ++j)
                rv[nb][j] = __builtin_nontemporal_load(&rp[j * 64 + lane]);
        }

        // Dot with cur from LDS; 4 independent accumulators.
        float s0 = 0.f, s1 = 0.f, s2 = 0.f, s3 = 0.f;
#pragma unroll
        for (int j = 0; j < 16; j += 4) {
            v4f a0 = rv[cb][j + 0], c0 = shbuf[(j + 0) * 64 + lane];
            v4f a1 = rv[cb][j + 1], c1 = shbuf[(j + 1) * 64 + lane];
            v4f a2 = rv[cb][j + 2], c2 = shbuf[(j + 2) * 64 + lane];
            v4f a3 = rv[cb][j + 3], c3 = shbuf[(j + 3) * 64 + lane];
            s0 = fmaf(a0[0], c0[0], fmaf(a0[1], c0[1], fmaf(a0[2], c0[2], fmaf(a0[3], c0[3], s0))));
            s1 = fmaf(a1[0], c1[0], fmaf(a1[1], c1[1], fmaf(a1[2], c1[2], fmaf(a1[3], c1[3], s1))));
            s2 = fmaf(a2[0], c2[0], fmaf(a2[1], c2[1], fmaf(a2[2], c2[2], fmaf(a2[3], c2[3], s2))));
            s3 = fmaf(a3[0], c3[0], fmaf(a3[1], c3[1], fmaf(a3[2], c3[2], fmaf(a3[3], c3[3], s3))));
        }
        float s = wave_sum_all((s0 + s1) + (s2 + s3));   // all lanes get the dot

        const float e = expf(s * scale);
        const float w = weights[row] * expf(-LAMBDA_DECAY * fabsf(tn - ts[row]));
        const float p = e * w;
        E += e; S += p;

#pragma unroll
        for (int j = 0; j < 16; ++j)
            acc[j] += p * rv[cb][j];
    }

    // Epilogue: combine 4 wave-accs in LDS (reuse shbuf after barrier).
    __syncthreads();                 // everyone done reading cur from shbuf
    if (wid == 0) {
#pragma unroll
        for (int j = 0; j < 16; ++j) shbuf[j * 64 + lane] = acc[j];
        if (lane == 0) { shE[0] = E; shS[0] = S; }
    }
    __syncthreads();
    for (int w = 1; w < WPB; ++w) {
        if (wid == w) {
#pragma unroll
            for (int j = 0; j < 16; ++j)
                shbuf[j * 64 + lane] += acc[j];
            if (lane == 0) { shE[w] = E; shS[w] = S; }
        }
        __syncthreads();
    }

    v4f* pb = (v4f*)(partial + (size_t)blockIdx.x * D);
#pragma unroll
    for (int jj = 0; jj < 4; ++jj)
        pb[jj * 256 + threadIdx.x] = shbuf[jj * 256 + threadIdx.x];
    if (threadIdx.x == 0) {
        float e = 0.f, sp = 0.f;
        for (int w = 0; w < WPB; ++w) { e += shE[w]; sp += shS[w]; }
        partE[blockIdx.x] = e;
        partS[blockIdx.x] = sp;
    }
}

// K2: tree-reduce partials 512 -> 8 per column. grid=(D/256, NP2).
__global__ __launch_bounds__(256) void reduce_kernel(
    const float* __restrict__ partial, float* __restrict__ partial2, int D)
{
    const int col = blockIdx.x * 256 + threadIdx.x;
    const int b0 = blockIdx.y * G2;
    float a0 = 0.0f, a1 = 0.0f;
    for (int b = 0; b < G2; b += 2) {
        a0 += partial[(size_t)(b0 + b) * D + col];
        a1 += partial[(size_t)(b0 + b + 1) * D + col];
    }
    partial2[(size_t)blockIdx.y * D + col] = a0 + a1;
}

// K3: final 8-way column sum + E/S reduce -> inv; blend; LayerNorm. 1 block.
__global__ __launch_bounds__(1024) void finalize_kernel(
    const float* __restrict__ partial2, const float* __restrict__ partE,
    const float* __restrict__ partS, const float* __restrict__ cur,
    float* __restrict__ out, int D)
{
    __shared__ float sh[16];
    const int tid = threadIdx.x;

    float E = 0.0f, S = 0.0f;
    for (int i = tid; i < NPART; i += 1024) { E += partE[i]; S += partS[i]; }
    E = block_sum(E, sh, 16);
    S = block_sum(S, sh, 16);
    const float inv = 1.0f / (S + 1e-9f * E);

    float v[4];
    float s = 0.0f, s2 = 0.0f;
#pragma unroll
    for (int k = 0; k < 4; ++k) {
        const int c = tid + k * 1024;
        float a = 0.0f;
#pragma unroll
        for (int y = 0; y < NP2; ++y) a += partial2[y * D + c];
        const float nv = ALPHA * cur[c] + (1.0f - ALPHA) * (a * inv);
        v[k] = nv;
        s += nv; s2 += nv * nv;
    }
    s = block_sum(s, sh, 16);
    s2 = block_sum(s2, sh, 16);
    const float mean = s / (float)D;
    const float var = s2 / (float)D - mean * mean;
    const float rstd = 1.0f / sqrtf(var + LN_EPS);
#pragma unroll
    for (int k = 0; k < 4; ++k)
        out[tid + k * 1024] = (v[k] - mean) * rstd;
}

extern "C" void kernel_launch(void* const* d_in, const int* in_sizes, int n_in,
                              void* d_out, int out_size, void* d_ws, size_t ws_size,
                              hipStream_t stream) {
    const float* states     = (const float*)d_in[0];
    const float* weights    = (const float*)d_in[1];
    const float* timestamps = (const float*)d_in[2];
    const float* current    = (const float*)d_in[3];
    // d_in[4] = sensed_state: not used in the output math.
    const float* t_new      = (const float*)d_in[5];
    float* out = (float*)d_out;

    const int M = in_sizes[1];   // 8192
    const int D = in_sizes[3];   // 4096

    float* ws       = (float*)d_ws;
    float* partial  = ws;                              // [NPART * D] (8 MiB)
    float* partial2 = partial + (size_t)NPART * D;     // [NP2 * D]
    float* partE    = partial2 + (size_t)NP2 * D;      // [NPART]
    float* partS    = partE + NPART;                   // [NPART]

    const float scale = 1.0f / sqrtf((float)D);

    fused_kernel<<<NPART, 256, 0, stream>>>(
        states, current, weights, timestamps, t_new,
        partial, partE, partS, M, D, scale);

    {
        dim3 grid(D / 256, NP2);   // (16, 8)
        reduce_kernel<<<grid, 256, 0, stream>>>(partial, partial2, D);
    }

    finalize_kernel<<<1, 1024, 0, stream>>>(partial2, partE, partS, current, out, D);
}

// Round 6
// 37.211 us; speedup vs baseline: 1.2926x; 1.2926x over previous
//
#include <hip/hip_runtime.h>
#include <math.h>

#define LAMBDA_DECAY 0.01f
#define ALPHA 0.95f
#define LN_EPS 1e-5f

// Geometry (reference: M=8192, D=4096).
#define NB 512       // K1 blocks
#define RPB 16       // rows per block = M/NB
#define WPB 8        // waves per block (512 threads); wave owns D/8 = 512 cols
#define G2 64        // partials per K2 block
#define NP2 8        // NB/G2

typedef float v4f __attribute__((ext_vector_type(4)));

static __device__ __forceinline__ float wave_sum_all(float v) {
#pragma unroll
    for (int o = 32; o > 0; o >>= 1) v += __shfl_xor(v, o);
    return v;
}

static __device__ float block_sum(float v, float* sh, int nwaves) {
    int lane = threadIdx.x & 63;
    int w = threadIdx.x >> 6;
    v = wave_sum_all(v);
    if (lane == 0) sh[w] = v;
    __syncthreads();
    float r = 0.0f;
    for (int i = 0; i < nwaves; ++i) r += sh[i];
    __syncthreads();
    return r;
}

// K1: single pass over states. 8 waves per block; wave w owns a 512-float
// D-slice (2 float4/lane). Per row: prefetch next row's slice (2 loads in
// flight, compiler emits counted vmcnt), partial dot, shuffle-reduce,
// exchange 8 partials via double-buffered LDS (one barrier/row), then
// acc += p * slice. Waves own disjoint slices -> no acc combine at end.
// Per-wave VGPR state ~60 -> high occupancy; memory-bound by design.
__global__ __launch_bounds__(512) void fused_kernel(
    const float* __restrict__ states, const float* __restrict__ cur,
    const float* __restrict__ weights, const float* __restrict__ ts,
    const float* __restrict__ t_new,
    float* __restrict__ partial, float* __restrict__ partE, float* __restrict__ partS,
    int M, int D, float scale)
{
    __shared__ float shp[2][WPB];

    const int wid = threadIdx.x >> 6;
    const int lane = threadIdx.x & 63;
    const int r0 = blockIdx.x * RPB;
    const int f4base = wid * 128 + lane;     // float4 index of this lane's first elem
    const int rstride = D >> 2;              // row stride in float4 (1024)

    const float tn = t_new[0];

    const v4f* c4 = (const v4f*)cur;
    const v4f curp0 = c4[f4base];
    const v4f curp1 = c4[f4base + 64];

    v4f acc0 = (v4f)(0.0f), acc1 = (v4f)(0.0f);
    float E = 0.0f, S = 0.0f;

    const v4f* sp = (const v4f*)states;

    v4f rv[2][2];
    rv[0][0] = sp[(size_t)r0 * rstride + f4base];
    rv[0][1] = sp[(size_t)r0 * rstride + f4base + 64];

#pragma unroll
    for (int r = 0; r < RPB; ++r) {
        const int row = r0 + r;
        const int cb = r & 1;        // compile-time after full unroll
        const int nb = cb ^ 1;

        if (r + 1 < RPB) {
            rv[nb][0] = sp[(size_t)(row + 1) * rstride + f4base];
            rv[nb][1] = sp[(size_t)(row + 1) * rstride + f4base + 64];
        }

        const v4f a0 = rv[cb][0], a1 = rv[cb][1];

        float d0 = 0.0f, d1 = 0.0f;
        d0 = fmaf(a0[0], curp0[0], d0); d1 = fmaf(a1[0], curp1[0], d1);
        d0 = fmaf(a0[1], curp0[1], d0); d1 = fmaf(a1[1], curp1[1], d1);
        d0 = fmaf(a0[2], curp0[2], d0); d1 = fmaf(a1[2], curp1[2], d1);
        d0 = fmaf(a0[3], curp0[3], d0); d1 = fmaf(a1[3], curp1[3], d1);
        float pd = wave_sum_all(d0 + d1);

        if (lane == 0) shp[cb][wid] = pd;
        __syncthreads();

        float s = 0.0f;
#pragma unroll
        for (int w = 0; w < WPB; ++w) s += shp[cb][w];   // same addr all lanes: broadcast
        s *= scale;

        const float e = expf(s);
        const float wgt = weights[row] * expf(-LAMBDA_DECAY * fabsf(tn - ts[row]));
        const float p = e * wgt;
        E += e; S += p;                                   // uniform across threads

        acc0 += p * a0;
        acc1 += p * a1;
    }

    v4f* pb = (v4f*)(partial + (size_t)blockIdx.x * D);
    pb[f4base] = acc0;
    pb[f4base + 64] = acc1;
    if (threadIdx.x == 0) {
        partE[blockIdx.x] = E;
        partS[blockIdx.x] = S;
    }
}

// K2: tree-reduce partials NB -> NP2 per column. grid=(D/256, NP2).
__global__ __launch_bounds__(256) void reduce_kernel(
    const float* __restrict__ partial, float* __restrict__ partial2, int D)
{
    const int col = blockIdx.x * 256 + threadIdx.x;
    const int b0 = blockIdx.y * G2;
    float a0 = 0.0f, a1 = 0.0f;
    for (int b = 0; b < G2; b += 2) {
        a0 += partial[(size_t)(b0 + b) * D + col];
        a1 += partial[(size_t)(b0 + b + 1) * D + col];
    }
    partial2[(size_t)blockIdx.y * D + col] = a0 + a1;
}

// K3: final NP2-way column sum + E/S reduce -> inv; blend; LayerNorm. 1 block.
__global__ __launch_bounds__(1024) void finalize_kernel(
    const float* __restrict__ partial2, const float* __restrict__ partE,
    const float* __restrict__ partS, const float* __restrict__ cur,
    float* __restrict__ out, int D)
{
    __shared__ float sh[16];
    const int tid = threadIdx.x;

    float E = 0.0f, S = 0.0f;
    for (int i = tid; i < NB; i += 1024) { E += partE[i]; S += partS[i]; }
    E = block_sum(E, sh, 16);
    S = block_sum(S, sh, 16);
    const float inv = 1.0f / (S + 1e-9f * E);

    float v[4];
    float s = 0.0f, s2 = 0.0f;
#pragma unroll
    for (int k = 0; k < 4; ++k) {
        const int c = tid + k * 1024;
        float a = 0.0f;
#pragma unroll
        for (int y = 0; y < NP2; ++y) a += partial2[y * D + c];
        const float nv = ALPHA * cur[c] + (1.0f - ALPHA) * (a * inv);
        v[k] = nv;
        s += nv; s2 += nv * nv;
    }
    s = block_sum(s, sh, 16);
    s2 = block_sum(s2, sh, 16);
    const float mean = s / (float)D;
    const float var = s2 / (float)D - mean * mean;
    const float rstd = 1.0f / sqrtf(var + LN_EPS);
#pragma unroll
    for (int k = 0; k < 4; ++k)
        out[tid + k * 1024] = (v[k] - mean) * rstd;
}

extern "C" void kernel_launch(void* const* d_in, const int* in_sizes, int n_in,
                              void* d_out, int out_size, void* d_ws, size_t ws_size,
                              hipStream_t stream) {
    const float* states     = (const float*)d_in[0];
    const float* weights    = (const float*)d_in[1];
    const float* timestamps = (const float*)d_in[2];
    const float* current    = (const float*)d_in[3];
    // d_in[4] = sensed_state: not used in the output math.
    const float* t_new      = (const float*)d_in[5];
    float* out = (float*)d_out;

    const int M = in_sizes[1];   // 8192
    const int D = in_sizes[3];   // 4096

    float* ws       = (float*)d_ws;
    float* partial  = ws;                              // [NB * D] (8 MiB)
    float* partial2 = partial + (size_t)NB * D;        // [NP2 * D]
    float* partE    = partial2 + (size_t)NP2 * D;      // [NB]
    float* partS    = partE + NB;                      // [NB]

    const float scale = 1.0f / sqrtf((float)D);

    fused_kernel<<<NB, 512, 0, stream>>>(
        states, current, weights, timestamps, t_new,
        partial, partE, partS, M, D, scale);

    {
        dim3 grid(D / 256, NP2);   // (16, 8)
        reduce_kernel<<<grid, 256, 0, stream>>>(partial, partial2, D);
    }

    finalize_kernel<<<1, 1024, 0, stream>>>(partial2, partE, partS, current, out, D);
}